// Round 3
// baseline (1044.769 us; speedup 1.0000x reference)
//
#include <hip/hip_runtime.h>
#include <math.h>

// Swin block: B=8 H=W=128 C=256 NH=8 HD=32 WS=8 SS=4, N=64 tokens/window,
// 2048 windows, 131072 tokens.

#define NWIN_TOTAL 2048
#define TOK_TOTAL  131072
#define SCALE_Q    0.17677669529663687f  // 32^-0.5

typedef unsigned short u16;
typedef __attribute__((ext_vector_type(4))) unsigned short u16x4;
typedef __attribute__((ext_vector_type(8))) unsigned short u16x8;
typedef __attribute__((ext_vector_type(8))) short bf16x8;   // MFMA A/B frag (4 VGPR)
typedef __attribute__((ext_vector_type(4))) float f32x4;    // MFMA C/D frag

#define AS1 __attribute__((address_space(1)))
#define AS3 __attribute__((address_space(3)))
#define GLOAD_LDS16(g, l) \
  __builtin_amdgcn_global_load_lds((const AS1 unsigned int*)(g), (AS3 unsigned int*)(l), 16, 0, 0)

__device__ __forceinline__ float bf2f(u16 u) {
  union { unsigned int i; float f; } c; c.i = ((unsigned int)u) << 16; return c.f;
}
__device__ __forceinline__ u16 f2bf(float f) {
  union { float f; unsigned int i; } c; c.f = f;
  return (u16)((c.i + 0x7fff + ((c.i >> 16) & 1)) >> 16);
}
__device__ __forceinline__ int regid3(int h) { return h < 120 ? 0 : (h < 124 ? 1 : 2); }
__device__ __forceinline__ float gelu_f(float v) {
  return 0.5f * v * (1.0f + erff(v * 0.7071067811865475f));
}

// (window g, token n) -> flat token index in image space (shift applied)
__device__ __forceinline__ int win_tok_to_t(int g, int n) {
  int b = g >> 8, wi = g & 255;
  int wr = wi >> 4, wc = wi & 15;
  int hs = wr * 8 + (n >> 3), ws2 = wc * 8 + (n & 7);
  int h = (hs + 4) & 127, w = (ws2 + 4) & 127;
  return (b << 14) + (h << 7) + w;
}

// ---------------- weight convert + transpose: [K][N] f32 -> [N][K] bf16 ----------------
__global__ __launch_bounds__(256)
void wconv_kernel(const float* __restrict__ w, u16* __restrict__ wt, int K, int N)
{
  int i = blockIdx.x * 256 + threadIdx.x;
  if (i >= K * N) return;
  int k = i / N, n = i - k * N;
  wt[(size_t)n * K + k] = f2bf(w[i]);
}

// ---------------- LN1 (gather into window order), bf16 out ----------------
__global__ __launch_bounds__(256)
void ln1_kernel(const float* __restrict__ x, const float* __restrict__ g1,
                const float* __restrict__ b1, u16* __restrict__ outw, int g0)
{
  int gid  = blockIdx.x * 4 + (threadIdx.x >> 6);
  int lane = threadIdx.x & 63;
  int g = g0 + (gid >> 6);
  int t = win_tok_to_t(g, gid & 63);
  float4 v = ((const float4*)x)[(size_t)t * 64 + lane];
  float s = v.x + v.y + v.z + v.w;
  float q = v.x * v.x + v.y * v.y + v.z * v.z + v.w * v.w;
#pragma unroll
  for (int m = 1; m < 64; m <<= 1) { s += __shfl_xor(s, m, 64); q += __shfl_xor(q, m, 64); }
  float mean = s * 0.00390625f;
  float var  = q * 0.00390625f - mean * mean;
  float rstd = rsqrtf(var + 1e-5f);
  float4 gg = ((const float4*)g1)[lane];
  float4 bb = ((const float4*)b1)[lane];
  u16x4 o;
  o.x = f2bf((v.x - mean) * rstd * gg.x + bb.x);
  o.y = f2bf((v.y - mean) * rstd * gg.y + bb.y);
  o.z = f2bf((v.z - mean) * rstd * gg.z + bb.z);
  o.w = f2bf((v.w - mean) * rstd * gg.w + bb.w);
  *(u16x4*)(outw + (size_t)gid * 256 + lane * 4) = o;
}

// ---------------- LN2, bf16 out ----------------
__global__ __launch_bounds__(256)
void ln2_kernel(const float* __restrict__ x2, const float* __restrict__ g2,
                const float* __restrict__ b2, u16* __restrict__ outw)
{
  int t    = blockIdx.x * 4 + (threadIdx.x >> 6);
  int lane = threadIdx.x & 63;
  float4 v = ((const float4*)x2)[(size_t)t * 64 + lane];
  float s = v.x + v.y + v.z + v.w;
  float q = v.x * v.x + v.y * v.y + v.z * v.z + v.w * v.w;
#pragma unroll
  for (int m = 1; m < 64; m <<= 1) { s += __shfl_xor(s, m, 64); q += __shfl_xor(q, m, 64); }
  float mean = s * 0.00390625f;
  float var  = q * 0.00390625f - mean * mean;
  float rstd = rsqrtf(var + 1e-5f);
  float4 gg = ((const float4*)g2)[lane];
  float4 bb = ((const float4*)b2)[lane];
  u16x4 o;
  o.x = f2bf((v.x - mean) * rstd * gg.x + bb.x);
  o.y = f2bf((v.y - mean) * rstd * gg.y + bb.y);
  o.z = f2bf((v.z - mean) * rstd * gg.z + bb.z);
  o.w = f2bf((v.w - mean) * rstd * gg.w + bb.w);
  *(u16x4*)(outw + (size_t)t * 256 + lane * 4) = o;
}

// ---------------- bf16 MFMA GEMM, 128x128 tile, BK=32, double-buffered LDS ----------------
// A: [M][K] bf16.  Bt: [N][K] bf16 (pre-transposed weight).
// MODE 0: +bias +x residual, scatter via win_tok_to_t -> o (f32)  (proj fused w/ shift-reverse)
// MODE 1: +bias, q-scale, scatter q/k/v bf16                      (qkv)
// MODE 2: +bias, GELU -> h (bf16)                                 (fc1)
// MODE 3: +bias +resid -> o (f32)                                 (fc2)
struct BArgs {
  const u16* A; const u16* Bt; const float* bias;
  float* o; u16* h; u16* q; u16* k; u16* v;
  const float* resid; const float* x;
  int M, N, K, g0;
};

template<int MODE>
__global__ __launch_bounds__(256)
void bgemm_kernel(BArgs a)
{
  __shared__ u16 As[2][4096];   // [buf][128 rows][32 k]
  __shared__ u16 Bs[2][4096];   // [buf][128 cols][32 k]
  const int tid  = threadIdx.x;
  const int wid  = tid >> 6, lane = tid & 63;
  const int wr   = wid >> 1, wc = wid & 1;
  // XCD-aware bijective swizzle (m204): consecutive logical ids on one XCD,
  // column-tile fastest -> all col tiles of a row panel share an XCD's L2.
  const int gx = gridDim.x;
  const int nwg = gx * gridDim.y;
  const int p = blockIdx.y * gx + blockIdx.x;
  const int qq = nwg >> 3, rr = nwg & 7, xcd = p & 7;
  const int l = (xcd < rr ? xcd * (qq + 1) : rr * (qq + 1) + (xcd - rr) * qq) + (p >> 3);
  const int rowBase = (l / gx) * 128;
  const int colBase = (l % gx) * 128;
  const int lr = lane >> 2;          // row within 16-row staging group
  const int lc = (lane & 3) * 8;     // k-element offset (16B granules)
  const int l15 = lane & 15, lhi = lane >> 4;

  f32x4 acc[4][4];
#pragma unroll
  for (int m = 0; m < 4; ++m)
#pragma unroll
    for (int n = 0; n < 4; ++n) acc[m][n] = (f32x4){0.f, 0.f, 0.f, 0.f};

  const int nkt = a.K >> 5;

#define STAGE(buf, kk)                                                          \
  {                                                                             \
    _Pragma("unroll")                                                           \
    for (int i = 0; i < 2; ++i) {                                               \
      const int srow = wid * 32 + i * 16;                                       \
      GLOAD_LDS16(a.A  + (size_t)(rowBase + srow + lr) * a.K + (kk) + lc,       \
                  &As[buf][srow * 32]);                                         \
      GLOAD_LDS16(a.Bt + (size_t)(colBase + srow + lr) * a.K + (kk) + lc,       \
                  &Bs[buf][srow * 32]);                                         \
    }                                                                           \
  }

  STAGE(0, 0);
  __syncthreads();
  int cur = 0;
  for (int kt = 0; kt < nkt; ++kt) {
    if (kt + 1 < nkt) STAGE(cur ^ 1, (kt + 1) << 5);
    bf16x8 af[4], bfr[4];
#pragma unroll
    for (int m = 0; m < 4; ++m)
      af[m] = *(const bf16x8*)&As[cur][(wr * 64 + m * 16 + l15) * 32 + lhi * 8];
#pragma unroll
    for (int n = 0; n < 4; ++n)
      bfr[n] = *(const bf16x8*)&Bs[cur][(wc * 64 + n * 16 + l15) * 32 + lhi * 8];
#pragma unroll
    for (int m = 0; m < 4; ++m)
#pragma unroll
      for (int n = 0; n < 4; ++n)
        acc[m][n] = __builtin_amdgcn_mfma_f32_16x16x32_bf16(af[m], bfr[n], acc[m][n], 0, 0, 0);
    __syncthreads();
    cur ^= 1;
  }
#undef STAGE

  // ---- epilogue: lane l, reg r holds D[row=(l>>4)*4+r][col=l&15] of each 16x16 frag ----
#pragma unroll
  for (int n = 0; n < 4; ++n) {
    const int col16 = colBase + wc * 64 + n * 16;
    const int col = col16 + l15;
    const float bv = a.bias[col];
    u16* qdst = nullptr; float scl = 1.f; size_t obase = 0;
    if (MODE == 1) {
      const int s = col16 >> 8, head = (col16 >> 5) & 7, hd = col16 & 31;
      qdst = (s == 0) ? a.q : (s == 1) ? a.k : a.v;
      if (s == 0) scl = SCALE_Q;
      obase = ((size_t)head << 11) + hd + l15;
    }
#pragma unroll
    for (int m = 0; m < 4; ++m) {
      const int row0 = rowBase + wr * 64 + m * 16 + lhi * 4;
#pragma unroll
      for (int r = 0; r < 4; ++r) {
        const int row = row0 + r;
        const float v = acc[m][n][r] + bv;
        if (MODE == 0) {
          const int t = win_tok_to_t(a.g0 + (row >> 6), row & 63);
          a.o[(size_t)t * 256 + col] = v + a.x[(size_t)t * 256 + col];
        } else if (MODE == 1) {
          const int gw = row >> 6, tok = row & 63;
          qdst[((size_t)gw << 14) + obase + ((size_t)tok << 5)] = f2bf(v * scl);
        } else if (MODE == 2) {
          a.h[(size_t)row * a.N + col] = f2bf(gelu_f(v));
        } else {
          a.o[(size_t)row * 256 + col] = v + a.resid[(size_t)row * 256 + col];
        }
      }
    }
  }
}

// ---------------- windowed attention: one wave per (window, head), bf16 in/out ----------------
__global__ __launch_bounds__(64)
void attn_kernel(const u16* __restrict__ qb, const u16* __restrict__ kb,
                 const u16* __restrict__ vb, const float* __restrict__ rpb,
                 u16* __restrict__ ao, int g0)
{
  __shared__ float kls[64 * 32];
  __shared__ float vls[64 * 32];
  int bw = blockIdx.x >> 3;
  int hh = blockIdx.x & 7;
  int lane = threadIdx.x;
  size_t base = ((size_t)((bw << 3) + hh)) << 11;
  const u16* ks = kb + base + lane * 32;
  const u16* vs = vb + base + lane * 32;
#pragma unroll
  for (int c = 0; c < 4; ++c) {
    u16x8 kv = *(const u16x8*)(ks + c * 8);
    u16x8 vv = *(const u16x8*)(vs + c * 8);
    float4 k0 = make_float4(bf2f(kv[0]), bf2f(kv[1]), bf2f(kv[2]), bf2f(kv[3]));
    float4 k1 = make_float4(bf2f(kv[4]), bf2f(kv[5]), bf2f(kv[6]), bf2f(kv[7]));
    float4 v0 = make_float4(bf2f(vv[0]), bf2f(vv[1]), bf2f(vv[2]), bf2f(vv[3]));
    float4 v1 = make_float4(bf2f(vv[4]), bf2f(vv[5]), bf2f(vv[6]), bf2f(vv[7]));
    *(float4*)(kls + lane * 32 + c * 8)     = k0;
    *(float4*)(kls + lane * 32 + c * 8 + 4) = k1;
    *(float4*)(vls + lane * 32 + c * 8)     = v0;
    *(float4*)(vls + lane * 32 + c * 8 + 4) = v1;
  }
  __syncthreads();
  float qr[32];
  const u16* qs = qb + base + lane * 32;
#pragma unroll
  for (int c = 0; c < 4; ++c) {
    u16x8 qv = *(const u16x8*)(qs + c * 8);
#pragma unroll
    for (int j = 0; j < 8; ++j) qr[c * 8 + j] = bf2f(qv[j]);
  }
  int g = g0 + bw;
  int wi = g & 255, wrw = wi >> 4, wcw = wi & 15;
  int i1 = lane >> 3, j1 = lane & 7;
  bool edge = (wrw == 15) || (wcw == 15);
  int rid1 = regid3(wrw * 8 + i1) * 3 + regid3(wcw * 8 + j1);
  float S[64];
  float mx = -1e30f;
#pragma unroll
  for (int m = 0; m < 64; ++m) {
    const float4* kr = (const float4*)(kls + m * 32);
    float s = 0.f;
#pragma unroll
    for (int c = 0; c < 8; ++c) {
      float4 kv = kr[c];
      s += qr[c*4+0]*kv.x + qr[c*4+1]*kv.y + qr[c*4+2]*kv.z + qr[c*4+3]*kv.w;
    }
    int i2 = m >> 3, j2 = m & 7;
    int idx = (i1 - i2 + 7) * 15 + (j1 - j2 + 7);
    s += rpb[idx * 8 + hh];
    if (edge) {
      int rid2 = regid3(wrw * 8 + i2) * 3 + regid3(wcw * 8 + j2);
      if (rid2 != rid1) s -= 100.f;
    }
    S[m] = s;
    mx = fmaxf(mx, s);
  }
  float sum = 0.f;
#pragma unroll
  for (int m = 0; m < 64; ++m) { float p = expf(S[m] - mx); S[m] = p; sum += p; }
  float inv = 1.f / sum;
  float acc[32];
#pragma unroll
  for (int c = 0; c < 32; ++c) acc[c] = 0.f;
#pragma unroll
  for (int m = 0; m < 64; ++m) {
    float p = S[m];
    const float4* vr = (const float4*)(vls + m * 32);
#pragma unroll
    for (int c = 0; c < 8; ++c) {
      float4 vv = vr[c];
      acc[c*4+0] += p * vv.x; acc[c*4+1] += p * vv.y;
      acc[c*4+2] += p * vv.z; acc[c*4+3] += p * vv.w;
    }
  }
  u16* dst = ao + ((size_t)((bw << 6) + lane)) * 256 + hh * 32;
#pragma unroll
  for (int c = 0; c < 4; ++c) {
    u16x8 o8;
#pragma unroll
    for (int j = 0; j < 8; ++j) o8[j] = f2bf(acc[c * 8 + j] * inv);
    *(u16x8*)(dst + c * 8) = o8;
  }
}

// ---------------- launch ----------------
extern "C" void kernel_launch(void* const* d_in, const int* in_sizes, int n_in,
                              void* d_out, int out_size, void* d_ws, size_t ws_size,
                              hipStream_t stream)
{
  const float* x      = (const float*)d_in[0];
  const float* qkv_w  = (const float*)d_in[1];
  const float* qkv_b  = (const float*)d_in[2];
  const float* proj_w = (const float*)d_in[3];
  const float* proj_b = (const float*)d_in[4];
  const float* rpb    = (const float*)d_in[5];
  const float* g1     = (const float*)d_in[6];
  const float* b1     = (const float*)d_in[7];
  const float* g2     = (const float*)d_in[8];
  const float* b2     = (const float*)d_in[9];
  const float* fc1_w  = (const float*)d_in[10];
  const float* fc1_b  = (const float*)d_in[11];
  const float* fc2_w  = (const float*)d_in[12];
  const float* fc2_b  = (const float*)d_in[13];
  float* out = (float*)d_out;
  char* ws = (char*)d_ws;

  // bf16 transposed weights
  u16* qkvT  = (u16*)ws;            // [768][256]
  u16* projT = qkvT + 196608;       // [256][256]
  u16* fc1T  = projT + 65536;       // [1024][256]
  u16* fc2T  = fc1T + 262144;       // [256][1024]
  u16* ln2w  = fc2T + 262144;       // [131072][256] bf16 = 64 MB
  char* pb = (char*)(ln2w + 33554432);
  size_t used = 1572864ULL + 67108864ULL;
  size_t R = ws_size > used ? ws_size - used : 0;

  wconv_kernel<<<(196608 + 255) / 256, 256, 0, stream>>>(qkv_w, qkvT, 256, 768);
  wconv_kernel<<<(65536  + 255) / 256, 256, 0, stream>>>(proj_w, projT, 256, 256);
  wconv_kernel<<<(262144 + 255) / 256, 256, 0, stream>>>(fc1_w, fc1T, 256, 1024);
  wconv_kernel<<<(262144 + 255) / 256, 256, 0, stream>>>(fc2_w, fc2T, 1024, 256);

  // attention-phase scratch per window: ln1w 32K + q/k/v 3*32K + ao 32K = 160K
  int Gc = 2048;
  while (Gc > 2 && (size_t)Gc * 163840ULL > R) Gc >>= 1;

  u16* ln1w = (u16*)pb;
  u16* qb = ln1w + (size_t)Gc * 16384;
  u16* kb = qb + (size_t)Gc * 16384;
  u16* vb = kb + (size_t)Gc * 16384;
  u16* ao = vb + (size_t)Gc * 16384;

  for (int g0 = 0; g0 < NWIN_TOTAL; g0 += Gc) {
    int nT = Gc * 64;
    ln1_kernel<<<nT / 4, 256, 0, stream>>>(x, g1, b1, ln1w, g0);

    BArgs qa = {}; qa.A = ln1w; qa.Bt = qkvT; qa.bias = qkv_b;
    qa.q = qb; qa.k = kb; qa.v = vb; qa.M = nT; qa.N = 768; qa.K = 256;
    bgemm_kernel<1><<<dim3(6, nT / 128), 256, 0, stream>>>(qa);

    attn_kernel<<<Gc * 8, 64, 0, stream>>>(qb, kb, vb, rpb, ao, g0);

    BArgs pa = {}; pa.A = ao; pa.Bt = projT; pa.bias = proj_b;
    pa.o = out; pa.x = x; pa.g0 = g0; pa.M = nT; pa.N = 256; pa.K = 256;
    bgemm_kernel<0><<<dim3(2, nT / 128), 256, 0, stream>>>(pa);
  }

  ln2_kernel<<<TOK_TOTAL / 4, 256, 0, stream>>>(out, g2, b2, ln2w);

  // MLP scratch: h1 = Tc*1024 bf16 = Tc*2048 B
  int Tc = TOK_TOTAL;
  while (Tc > 128 && (size_t)Tc * 2048ULL > R) Tc >>= 1;
  u16* h1 = (u16*)pb;
  for (int t0 = 0; t0 < TOK_TOTAL; t0 += Tc) {
    BArgs fa = {}; fa.A = ln2w + (size_t)t0 * 256; fa.Bt = fc1T; fa.bias = fc1_b;
    fa.h = h1; fa.M = Tc; fa.N = 1024; fa.K = 256;
    bgemm_kernel<2><<<dim3(8, Tc / 128), 256, 0, stream>>>(fa);

    BArgs fb = {}; fb.A = h1; fb.Bt = fc2T; fb.bias = fc2_b;
    fb.o = out + (size_t)t0 * 256; fb.resid = out + (size_t)t0 * 256;
    fb.M = Tc; fb.N = 256; fb.K = 1024;
    bgemm_kernel<3><<<dim3(2, Tc / 128), 256, 0, stream>>>(fb);
  }
}

// Round 4
// 886.392 us; speedup vs baseline: 1.1787x; 1.1787x over previous
//
#include <hip/hip_runtime.h>
#include <math.h>

// Swin block: B=8 H=W=128 C=256 NH=8 HD=32 WS=8 SS=4, N=64 tokens/window,
// 2048 windows, 131072 tokens.

#define NWIN_TOTAL 2048
#define TOK_TOTAL  131072
#define SCALE_Q    0.17677669529663687f  // 32^-0.5
#define LOG2E      1.4426950408889634f

typedef unsigned short u16;
typedef __attribute__((ext_vector_type(4))) unsigned short u16x4;
typedef __attribute__((ext_vector_type(8))) unsigned short u16x8;
typedef __attribute__((ext_vector_type(8))) short bf16x8;   // MFMA A/B frag (4 VGPR)
typedef __attribute__((ext_vector_type(4))) float f32x4;    // MFMA C/D frag

#define AS1 __attribute__((address_space(1)))
#define AS3 __attribute__((address_space(3)))
#define GLOAD_LDS16(g, l) \
  __builtin_amdgcn_global_load_lds((const AS1 unsigned int*)(g), (AS3 unsigned int*)(l), 16, 0, 0)

__device__ __forceinline__ float bf2f(u16 u) {
  union { unsigned int i; float f; } c; c.i = ((unsigned int)u) << 16; return c.f;
}
__device__ __forceinline__ u16 f2bf(float f) {
  union { float f; unsigned int i; } c; c.f = f;
  return (u16)((c.i + 0x7fff + ((c.i >> 16) & 1)) >> 16);
}
__device__ __forceinline__ int regid3(int h) { return h < 120 ? 0 : (h < 124 ? 1 : 2); }
__device__ __forceinline__ float gelu_f(float v) {
  return 0.5f * v * (1.0f + erff(v * 0.7071067811865475f));
}

// (window g, token n) -> flat token index in image space (shift applied)
__device__ __forceinline__ int win_tok_to_t(int g, int n) {
  int b = g >> 8, wi = g & 255;
  int wr = wi >> 4, wc = wi & 15;
  int hs = wr * 8 + (n >> 3), ws2 = wc * 8 + (n & 7);
  int h = (hs + 4) & 127, w = (ws2 + 4) & 127;
  return (b << 14) + (h << 7) + w;
}

// ---------------- weight convert + transpose: [K][N] f32 -> [N][K] bf16 ----------------
__global__ __launch_bounds__(256)
void wconv_kernel(const float* __restrict__ w, u16* __restrict__ wt, int K, int N)
{
  int i = blockIdx.x * 256 + threadIdx.x;
  if (i >= K * N) return;
  int k = i / N, n = i - k * N;
  wt[(size_t)n * K + k] = f2bf(w[i]);
}

// ---------------- LN1 (gather into window order), bf16 out ----------------
__global__ __launch_bounds__(256)
void ln1_kernel(const float* __restrict__ x, const float* __restrict__ g1,
                const float* __restrict__ b1, u16* __restrict__ outw, int g0)
{
  int gid  = blockIdx.x * 4 + (threadIdx.x >> 6);
  int lane = threadIdx.x & 63;
  int g = g0 + (gid >> 6);
  int t = win_tok_to_t(g, gid & 63);
  float4 v = ((const float4*)x)[(size_t)t * 64 + lane];
  float s = v.x + v.y + v.z + v.w;
  float q = v.x * v.x + v.y * v.y + v.z * v.z + v.w * v.w;
#pragma unroll
  for (int m = 1; m < 64; m <<= 1) { s += __shfl_xor(s, m, 64); q += __shfl_xor(q, m, 64); }
  float mean = s * 0.00390625f;
  float var  = q * 0.00390625f - mean * mean;
  float rstd = rsqrtf(var + 1e-5f);
  float4 gg = ((const float4*)g1)[lane];
  float4 bb = ((const float4*)b1)[lane];
  u16x4 o;
  o.x = f2bf((v.x - mean) * rstd * gg.x + bb.x);
  o.y = f2bf((v.y - mean) * rstd * gg.y + bb.y);
  o.z = f2bf((v.z - mean) * rstd * gg.z + bb.z);
  o.w = f2bf((v.w - mean) * rstd * gg.w + bb.w);
  *(u16x4*)(outw + (size_t)gid * 256 + lane * 4) = o;
}

// ---------------- LN2, bf16 out ----------------
__global__ __launch_bounds__(256)
void ln2_kernel(const float* __restrict__ x2, const float* __restrict__ g2,
                const float* __restrict__ b2, u16* __restrict__ outw)
{
  int t    = blockIdx.x * 4 + (threadIdx.x >> 6);
  int lane = threadIdx.x & 63;
  float4 v = ((const float4*)x2)[(size_t)t * 64 + lane];
  float s = v.x + v.y + v.z + v.w;
  float q = v.x * v.x + v.y * v.y + v.z * v.z + v.w * v.w;
#pragma unroll
  for (int m = 1; m < 64; m <<= 1) { s += __shfl_xor(s, m, 64); q += __shfl_xor(q, m, 64); }
  float mean = s * 0.00390625f;
  float var  = q * 0.00390625f - mean * mean;
  float rstd = rsqrtf(var + 1e-5f);
  float4 gg = ((const float4*)g2)[lane];
  float4 bb = ((const float4*)b2)[lane];
  u16x4 o;
  o.x = f2bf((v.x - mean) * rstd * gg.x + bb.x);
  o.y = f2bf((v.y - mean) * rstd * gg.y + bb.y);
  o.z = f2bf((v.z - mean) * rstd * gg.z + bb.z);
  o.w = f2bf((v.w - mean) * rstd * gg.w + bb.w);
  *(u16x4*)(outw + (size_t)t * 256 + lane * 4) = o;
}

// ---------------- bf16 MFMA GEMM, 128x128 tile, BK=32, double-buffered LDS ----------------
// MODE 0: +bias +x residual, scatter via win_tok_to_t -> o (f32)  (proj fused w/ shift-reverse)
// MODE 1: +bias; q,k scaled/token-major; v transposed [hd][tok]   (qkv)
// MODE 2: +bias, GELU -> h (bf16)                                 (fc1)
// MODE 3: +bias +resid -> o (f32)                                 (fc2)
struct BArgs {
  const u16* A; const u16* Bt; const float* bias;
  float* o; u16* h; u16* q; u16* k; u16* v;
  const float* resid; const float* x;
  int M, N, K, g0;
};

template<int MODE>
__global__ __launch_bounds__(256)
void bgemm_kernel(BArgs a)
{
  __shared__ u16 As[2][4096];   // [buf][128 rows][32 k]
  __shared__ u16 Bs[2][4096];   // [buf][128 cols][32 k]
  const int tid  = threadIdx.x;
  const int wid  = tid >> 6, lane = tid & 63;
  const int wr   = wid >> 1, wc = wid & 1;
  // XCD-aware bijective swizzle (m204), column-tile fastest within an XCD chunk
  const int gx = gridDim.x;
  const int nwg = gx * gridDim.y;
  const int p = blockIdx.y * gx + blockIdx.x;
  const int qq = nwg >> 3, rr = nwg & 7, xcd = p & 7;
  const int l = (xcd < rr ? xcd * (qq + 1) : rr * (qq + 1) + (xcd - rr) * qq) + (p >> 3);
  const int rowBase = (l / gx) * 128;
  const int colBase = (l % gx) * 128;
  const int lr = lane >> 2;
  const int lc = (lane & 3) * 8;
  const int l15 = lane & 15, lhi = lane >> 4;

  f32x4 acc[4][4];
#pragma unroll
  for (int m = 0; m < 4; ++m)
#pragma unroll
    for (int n = 0; n < 4; ++n) acc[m][n] = (f32x4){0.f, 0.f, 0.f, 0.f};

  const int nkt = a.K >> 5;

#define STAGE(buf, kk)                                                          \
  {                                                                             \
    _Pragma("unroll")                                                           \
    for (int i = 0; i < 2; ++i) {                                               \
      const int srow = wid * 32 + i * 16;                                       \
      GLOAD_LDS16(a.A  + (size_t)(rowBase + srow + lr) * a.K + (kk) + lc,       \
                  &As[buf][srow * 32]);                                         \
      GLOAD_LDS16(a.Bt + (size_t)(colBase + srow + lr) * a.K + (kk) + lc,       \
                  &Bs[buf][srow * 32]);                                         \
    }                                                                           \
  }

  STAGE(0, 0);
  __syncthreads();
  int cur = 0;
  for (int kt = 0; kt < nkt; ++kt) {
    if (kt + 1 < nkt) STAGE(cur ^ 1, (kt + 1) << 5);
    bf16x8 af[4], bfr[4];
#pragma unroll
    for (int m = 0; m < 4; ++m)
      af[m] = *(const bf16x8*)&As[cur][(wr * 64 + m * 16 + l15) * 32 + lhi * 8];
#pragma unroll
    for (int n = 0; n < 4; ++n)
      bfr[n] = *(const bf16x8*)&Bs[cur][(wc * 64 + n * 16 + l15) * 32 + lhi * 8];
#pragma unroll
    for (int m = 0; m < 4; ++m)
#pragma unroll
      for (int n = 0; n < 4; ++n)
        acc[m][n] = __builtin_amdgcn_mfma_f32_16x16x32_bf16(af[m], bfr[n], acc[m][n], 0, 0, 0);
    __syncthreads();
    cur ^= 1;
  }
#undef STAGE

  // ---- epilogue: lane l, reg r holds D[row=(l>>4)*4+r][col=l&15] ----
#pragma unroll
  for (int n = 0; n < 4; ++n) {
    const int col16 = colBase + wc * 64 + n * 16;
    const int col = col16 + l15;
    const float bv = a.bias[col];
    u16* qdst = nullptr; float scl = 1.f; size_t obase = 0;
    int vsel = 0;
    if (MODE == 1) {
      const int s = col16 >> 8, head = (col16 >> 5) & 7, hd = col16 & 31;
      if (s == 2) {
        vsel = 1;
        obase = ((size_t)head << 11) + (size_t)(hd + l15) * 64;   // vT [hd][tok]
      } else {
        qdst = (s == 0) ? a.q : a.k;
        if (s == 0) scl = SCALE_Q * LOG2E;   // fold log2e for exp2-domain softmax
        obase = ((size_t)head << 11) + hd + l15;
      }
    }
#pragma unroll
    for (int m = 0; m < 4; ++m) {
      const int row0 = rowBase + wr * 64 + m * 16 + lhi * 4;
      if (MODE == 1 && vsel) {
        const int gw = row0 >> 6, tok0 = row0 & 63;
        u16x4 pk;
#pragma unroll
        for (int r = 0; r < 4; ++r) pk[r] = f2bf(acc[m][n][r] + bv);
        *(u16x4*)&a.v[((size_t)gw << 14) + obase + tok0] = pk;
        continue;
      }
#pragma unroll
      for (int r = 0; r < 4; ++r) {
        const int row = row0 + r;
        const float v = acc[m][n][r] + bv;
        if (MODE == 0) {
          const int t = win_tok_to_t(a.g0 + (row >> 6), row & 63);
          a.o[(size_t)t * 256 + col] = v + a.x[(size_t)t * 256 + col];
        } else if (MODE == 1) {
          const int gw = row >> 6, tok = row & 63;
          qdst[((size_t)gw << 14) + obase + ((size_t)tok << 5)] = f2bf(v * scl);
        } else if (MODE == 2) {
          a.h[(size_t)row * a.N + col] = f2bf(gelu_f(v));
        } else {
          a.o[(size_t)row * 256 + col] = v + a.resid[(size_t)row * 256 + col];
        }
      }
    }
  }
}

// ---------------- MFMA windowed attention: one wave per (window, head) ----------------
// q,k: [win*8+head][64 tok][32 hd] bf16 (q pre-scaled by SCALE_Q*LOG2E)
// vt:  [win*8+head][32 hd][64 tok] bf16
// out ao: [win*64 + tok][256] bf16 (channel = head*32 + hd)
__global__ __launch_bounds__(256)
void attn_kernel(const u16* __restrict__ qb, const u16* __restrict__ kb,
                 const u16* __restrict__ vt, const float* __restrict__ rpb,
                 u16* __restrict__ ao, int g0)
{
  __shared__ float rl[1800];      // rpb re-layout: [head][di+7][dj2+7], *LOG2E
  __shared__ u16 pl[4][4096];     // per-wave P buffer, [n][m] bf16, XOR-swizzled
  const int tid = threadIdx.x, wid = tid >> 6, lane = tid & 63;
  // stage rpb: rl[hh*225 + a*15 + b] = rpb[(a*15 + 14-b)*8 + hh] * LOG2E
  for (int i = tid; i < 1800; i += 256) {
    unsigned int hh = (unsigned)i / 225u;
    unsigned int rem = (unsigned)i - hh * 225u;
    unsigned int aa = rem / 15u, bb = rem - aa * 15u;
    rl[i] = rpb[(aa * 15u + 14u - bb) * 8u + hh] * LOG2E;
  }
  __syncthreads();

  const int u = blockIdx.x * 4 + wid;
  const int bw = u >> 3, hh = u & 7;
  const size_t base = ((size_t)u) << 11;
  const int l15 = lane & 15, g = lane >> 4;

  // ---- S^T = K · Q^T : 16 MFMAs, lane owns column n = nf*16 + l15 ----
  bf16x8 qf[4], kf[4];
#pragma unroll
  for (int f = 0; f < 4; ++f) {
    qf[f] = *(const bf16x8*)(qb + base + (size_t)(f * 16 + l15) * 32 + g * 8);
    kf[f] = *(const bf16x8*)(kb + base + (size_t)(f * 16 + l15) * 32 + g * 8);
  }
  f32x4 acc[4][4];
#pragma unroll
  for (int mf = 0; mf < 4; ++mf)
#pragma unroll
    for (int nf = 0; nf < 4; ++nf) acc[mf][nf] = (f32x4){0.f, 0.f, 0.f, 0.f};
#pragma unroll
  for (int mf = 0; mf < 4; ++mf)
#pragma unroll
    for (int nf = 0; nf < 4; ++nf)
      acc[mf][nf] = __builtin_amdgcn_mfma_f32_16x16x32_bf16(kf[mf], qf[nf], acc[mf][nf], 0, 0, 0);

  // ---- bias + mask (log2 domain). m = mf*16 + g*4 + r ----
  const int gwin = g0 + bw;
  const int wrw = (gwin >> 4) & 15, wcw = gwin & 15;
  const bool edge = (wrw == 15) || (wcw == 15);
  const int i2b = g >> 1;            // i2 = mf*2 + i2b (r-independent)
  const int j2b = (g & 1) * 4;       // j2 = j2b + r
#pragma unroll
  for (int nf = 0; nf < 4; ++nf) {
    const int n = nf * 16 + l15;
    const int i1 = n >> 3, j1 = n & 7;
    const int rid1 = edge ? regid3(wrw * 8 + i1) * 3 + regid3(wcw * 8 + j1) : 0;
#pragma unroll
    for (int mf = 0; mf < 4; ++mf) {
      const int i2 = mf * 2 + i2b;
      const int ib = hh * 225 + (i1 - i2 + 7) * 15 + (j2b - j1 + 7);
      const int r2a = edge ? regid3(wrw * 8 + i2) * 3 : 0;
#pragma unroll
      for (int r = 0; r < 4; ++r) {
        float b = rl[ib + r];
        if (edge) {
          int rid2 = r2a + regid3(wcw * 8 + j2b + r);
          if (rid2 != rid1) b -= 144.2695f;
        }
        acc[mf][nf][r] += b;
      }
    }
  }

  // ---- softmax over m, per column n (16 lane-local + lanes n, n+16, n+32, n+48) ----
  float inv[4];
#pragma unroll
  for (int nf = 0; nf < 4; ++nf) {
    float m0 = -1e30f;
#pragma unroll
    for (int mf = 0; mf < 4; ++mf)
#pragma unroll
      for (int r = 0; r < 4; ++r) m0 = fmaxf(m0, acc[mf][nf][r]);
    m0 = fmaxf(m0, __shfl_xor(m0, 16, 64));
    m0 = fmaxf(m0, __shfl_xor(m0, 32, 64));
    float s = 0.f;
#pragma unroll
    for (int mf = 0; mf < 4; ++mf)
#pragma unroll
      for (int r = 0; r < 4; ++r) {
        float p = exp2f(acc[mf][nf][r] - m0);
        acc[mf][nf][r] = p;
        s += p;
      }
    s += __shfl_xor(s, 16, 64);
    s += __shfl_xor(s, 32, 64);
    inv[nf] = 1.f / s;
  }

  // ---- write P/sum to LDS [n][m] bf16, byte ^= (n&7)<<4 (bits 4-6) ----
  char* plw = (char*)pl[wid];
#pragma unroll
  for (int nf = 0; nf < 4; ++nf) {
    const int n = nf * 16 + l15;
    const int swz = (n & 7) << 4;
#pragma unroll
    for (int mf = 0; mf < 4; ++mf) {
      float p0 = acc[mf][nf][0] * inv[nf], p1 = acc[mf][nf][1] * inv[nf];
      float p2 = acc[mf][nf][2] * inv[nf], p3 = acc[mf][nf][3] * inv[nf];
      unsigned int pa, pb;
      asm("v_cvt_pk_bf16_f32 %0, %1, %2" : "=v"(pa) : "v"(p0), "v"(p1));
      asm("v_cvt_pk_bf16_f32 %0, %1, %2" : "=v"(pb) : "v"(p2), "v"(p3));
      uint2 w; w.x = pa; w.y = pb;
      *(uint2*)(plw + ((n * 128 + (mf * 16 + g * 4) * 2) ^ swz)) = w;
    }
  }

  // ---- O = P · V : A-frag = P rows (read back), B-frag = vT ----
  bf16x8 vf[2][2];
#pragma unroll
  for (int df = 0; df < 2; ++df)
#pragma unroll
    for (int ks = 0; ks < 2; ++ks)
      vf[df][ks] = *(const bf16x8*)(vt + base + (size_t)(df * 16 + l15) * 64 + ks * 32 + g * 8);
  f32x4 accO[4][2];
#pragma unroll
  for (int nf = 0; nf < 4; ++nf)
#pragma unroll
    for (int df = 0; df < 2; ++df) accO[nf][df] = (f32x4){0.f, 0.f, 0.f, 0.f};
#pragma unroll
  for (int nf = 0; nf < 4; ++nf) {
    const int n = nf * 16 + l15;
    const int swz = (n & 7) << 4;
#pragma unroll
    for (int ks = 0; ks < 2; ++ks) {
      bf16x8 pf = *(const bf16x8*)(plw + ((n * 128 + ks * 64 + g * 16) ^ swz));
#pragma unroll
      for (int df = 0; df < 2; ++df)
        accO[nf][df] = __builtin_amdgcn_mfma_f32_16x16x32_bf16(pf, vf[df][ks], accO[nf][df], 0, 0, 0);
    }
  }

  // ---- epilogue: O[tok = nf*16 + g*4 + r][d = df*16 + l15] ----
  u16* aob = ao + ((size_t)bw << 14) + hh * 32;
#pragma unroll
  for (int nf = 0; nf < 4; ++nf)
#pragma unroll
    for (int r = 0; r < 4; ++r) {
      const int tok = nf * 16 + g * 4 + r;
#pragma unroll
      for (int df = 0; df < 2; ++df)
        aob[(size_t)tok * 256 + df * 16 + l15] = f2bf(accO[nf][df][r]);
    }
}

// ---------------- launch ----------------
extern "C" void kernel_launch(void* const* d_in, const int* in_sizes, int n_in,
                              void* d_out, int out_size, void* d_ws, size_t ws_size,
                              hipStream_t stream)
{
  const float* x      = (const float*)d_in[0];
  const float* qkv_w  = (const float*)d_in[1];
  const float* qkv_b  = (const float*)d_in[2];
  const float* proj_w = (const float*)d_in[3];
  const float* proj_b = (const float*)d_in[4];
  const float* rpb    = (const float*)d_in[5];
  const float* g1     = (const float*)d_in[6];
  const float* b1     = (const float*)d_in[7];
  const float* g2     = (const float*)d_in[8];
  const float* b2     = (const float*)d_in[9];
  const float* fc1_w  = (const float*)d_in[10];
  const float* fc1_b  = (const float*)d_in[11];
  const float* fc2_w  = (const float*)d_in[12];
  const float* fc2_b  = (const float*)d_in[13];
  float* out = (float*)d_out;
  char* ws = (char*)d_ws;

  // bf16 transposed weights
  u16* qkvT  = (u16*)ws;            // [768][256]
  u16* projT = qkvT + 196608;       // [256][256]
  u16* fc1T  = projT + 65536;       // [1024][256]
  u16* fc2T  = fc1T + 262144;       // [256][1024]
  u16* ln2w  = fc2T + 262144;       // [131072][256] bf16 = 64 MB
  char* pb = (char*)(ln2w + 33554432);
  size_t used = 1572864ULL + 67108864ULL;
  size_t R = ws_size > used ? ws_size - used : 0;

  wconv_kernel<<<(196608 + 255) / 256, 256, 0, stream>>>(qkv_w, qkvT, 256, 768);
  wconv_kernel<<<(65536  + 255) / 256, 256, 0, stream>>>(proj_w, projT, 256, 256);
  wconv_kernel<<<(262144 + 255) / 256, 256, 0, stream>>>(fc1_w, fc1T, 256, 1024);
  wconv_kernel<<<(262144 + 255) / 256, 256, 0, stream>>>(fc2_w, fc2T, 1024, 256);

  // attention-phase scratch per window: ln1w 32K + q/k/v 3*32K + ao 32K = 160K
  int Gc = 2048;
  while (Gc > 2 && (size_t)Gc * 163840ULL > R) Gc >>= 1;

  u16* ln1w = (u16*)pb;
  u16* qb = ln1w + (size_t)Gc * 16384;
  u16* kb = qb + (size_t)Gc * 16384;
  u16* vb = kb + (size_t)Gc * 16384;   // stored transposed [hd][tok]
  u16* ao = vb + (size_t)Gc * 16384;

  for (int g0 = 0; g0 < NWIN_TOTAL; g0 += Gc) {
    int nT = Gc * 64;
    ln1_kernel<<<nT / 4, 256, 0, stream>>>(x, g1, b1, ln1w, g0);

    BArgs qa = {}; qa.A = ln1w; qa.Bt = qkvT; qa.bias = qkv_b;
    qa.q = qb; qa.k = kb; qa.v = vb; qa.M = nT; qa.N = 768; qa.K = 256;
    bgemm_kernel<1><<<dim3(6, nT / 128), 256, 0, stream>>>(qa);

    attn_kernel<<<Gc * 2, 256, 0, stream>>>(qb, kb, vb, rpb, ao, g0);

    BArgs pa = {}; pa.A = ao; pa.Bt = projT; pa.bias = proj_b;
    pa.o = out; pa.x = x; pa.g0 = g0; pa.M = nT; pa.N = 256; pa.K = 256;
    bgemm_kernel<0><<<dim3(2, nT / 128), 256, 0, stream>>>(pa);
  }

  ln2_kernel<<<TOK_TOTAL / 4, 256, 0, stream>>>(out, g2, b2, ln2w);

  // MLP scratch: h1 = Tc*1024 bf16 = Tc*2048 B
  int Tc = TOK_TOTAL;
  while (Tc > 128 && (size_t)Tc * 2048ULL > R) Tc >>= 1;
  u16* h1 = (u16*)pb;
  for (int t0 = 0; t0 < TOK_TOTAL; t0 += Tc) {
    BArgs fa = {}; fa.A = ln2w + (size_t)t0 * 256; fa.Bt = fc1T; fa.bias = fc1_b;
    fa.h = h1; fa.M = Tc; fa.N = 1024; fa.K = 256;
    bgemm_kernel<2><<<dim3(8, Tc / 128), 256, 0, stream>>>(fa);

    BArgs fb = {}; fb.A = h1; fb.Bt = fc2T; fb.bias = fc2_b;
    fb.o = out + (size_t)t0 * 256; fb.resid = out + (size_t)t0 * 256;
    fb.M = Tc; fb.N = 256; fb.K = 1024;
    bgemm_kernel<3><<<dim3(2, Tc / 128), 256, 0, stream>>>(fb);
  }
}